// Round 1
// baseline (1005.005 us; speedup 1.0000x reference)
//
#include <hip/hip_runtime.h>
#include <hip/hip_bf16.h>

constexpr int IN_C  = 128;
constexpr int HID_C = 256;
constexpr int OUT_C = 47;

// ---------------- CSR build ----------------

__global__ void count_edges(const int* __restrict__ dst, int* __restrict__ cnt, int E) {
  int e = blockIdx.x * blockDim.x + threadIdx.x;
  if (e < E) atomicAdd(&cnt[dst[e]], 1);
}

// Single-block Hillis-Steele scan over chunks of 1024 (N=100K -> 98 chunks, ~tens of us).
__global__ __launch_bounds__(1024) void scan_block(const int* __restrict__ cnt,
                                                   int* __restrict__ off, int N) {
  __shared__ int tmp[1024];
  const int tid = threadIdx.x;
  int carry = 0;
  for (int base = 0; base < N; base += 1024) {
    const int i = base + tid;
    const int v = (i < N) ? cnt[i] : 0;
    tmp[tid] = v;
    __syncthreads();
    for (int d = 1; d < 1024; d <<= 1) {
      const int t = (tid >= d) ? tmp[tid - d] : 0;
      __syncthreads();
      tmp[tid] += t;
      __syncthreads();
    }
    const int incl  = tmp[tid];
    const int total = tmp[1023];
    if (i < N) off[i] = carry + incl - v;   // exclusive prefix
    carry += total;
    __syncthreads();                         // protect tmp before next chunk
  }
  if (tid == 0) off[N] = carry;
}

__global__ void fill_csr(const int* __restrict__ src, const int* __restrict__ dst,
                         const int* __restrict__ off, int* __restrict__ cursor,
                         int* __restrict__ csr, int E) {
  int e = blockIdx.x * blockDim.x + threadIdx.x;
  if (e < E) {
    int d = dst[e];
    int p = atomicAdd(&cursor[d], 1);
    csr[off[d] + p] = src[e];
  }
}

// ---------------- layer-1 aggregation: mean1[d,:] = mean over in-edges of x[src,:] ----------------
// One wave (64 lanes) per dst node; each lane owns 2 of the 128 channels (float2 = 512B/edge).
__global__ __launch_bounds__(256) void agg1(const float* __restrict__ x,
                                            const int* __restrict__ off,
                                            const int* __restrict__ csr,
                                            float* __restrict__ mean1, int N) {
  const int wid  = (blockIdx.x * blockDim.x + threadIdx.x) >> 6;
  const int lane = threadIdx.x & 63;
  if (wid >= N) return;
  const int s0 = off[wid], s1 = off[wid + 1];
  float a0 = 0.f, a1 = 0.f;
  for (int e = s0; e < s1; ++e) {
    const int s = csr[e];                                   // wave-uniform (broadcast)
    const float2 v = *(const float2*)&x[(size_t)s * IN_C + lane * 2];
    a0 += v.x; a1 += v.y;
  }
  const int deg = s1 - s0;
  const float inv = (deg > 0) ? 1.0f / (float)deg : 0.0f;   // ref: sum / max(cnt,1)
  float2 m; m.x = a0 * inv; m.y = a1 * inv;
  *(float2*)&mean1[(size_t)wid * IN_C + lane * 2] = m;
}

// ---------------- GEMM1: h = relu([mean1 | x] @ [W1_l ; W1_r] + b1), bf16 out ----------------
// 64x64 tile, 256 threads, 4x4 per thread, K staged in 16-blocks, A transposed in LDS.
__global__ __launch_bounds__(256) void gemm1(const float* __restrict__ A0,   // mean1 [M,128]
                                             const float* __restrict__ A1,   // x     [M,128]
                                             const float* __restrict__ B0,   // W1_l  [128,256]
                                             const float* __restrict__ B1,   // W1_r  [128,256]
                                             const float* __restrict__ bias, // b1 [256]
                                             __hip_bfloat16* __restrict__ H, // [M,256]
                                             int M) {
  __shared__ float Ats[16][68];   // [k][row], row-stride 68 floats = 272B (16B aligned)
  __shared__ float Bs[16][64];    // [k][col]
  const int tid = threadIdx.x;
  const int r0 = blockIdx.x * 64;
  const int c0 = blockIdx.y * 64;
  const int ty4 = (tid >> 4) * 4;   // row group base (0..60)
  const int tx4 = (tid & 15) * 4;   // col group base (0..60)

  float acc[4][4];
  #pragma unroll
  for (int i = 0; i < 4; ++i)
    #pragma unroll
    for (int j = 0; j < 4; ++j) acc[i][j] = 0.f;

  const int row_l = tid >> 2;         // staging: A row 0..63
  const int kc    = (tid & 3) * 4;    // staging: A k sub-block
  const int k_r   = tid >> 4;         // staging: B k row 0..15
  const int nc    = (tid & 15) * 4;   // staging: B col

  #pragma unroll 1
  for (int p = 0; p < 2; ++p) {
    const float* __restrict__ A = p ? A1 : A0;
    const float* __restrict__ B = p ? B1 : B0;
    #pragma unroll 1
    for (int kb = 0; kb < 8; ++kb) {
      // stage A (64x16, transposed) and B (16x64)
      const int gr = r0 + row_l;
      float4 a4 = make_float4(0.f, 0.f, 0.f, 0.f);
      if (gr < M) a4 = *(const float4*)&A[(size_t)gr * IN_C + kb * 16 + kc];
      Ats[kc + 0][row_l] = a4.x;
      Ats[kc + 1][row_l] = a4.y;
      Ats[kc + 2][row_l] = a4.z;
      Ats[kc + 3][row_l] = a4.w;
      *(float4*)&Bs[k_r][nc] = *(const float4*)&B[(size_t)(kb * 16 + k_r) * HID_C + c0 + nc];
      __syncthreads();
      #pragma unroll
      for (int kk = 0; kk < 16; ++kk) {
        const float4 av = *(const float4*)&Ats[kk][ty4];
        const float4 bv = *(const float4*)&Bs[kk][tx4];
        const float a[4] = {av.x, av.y, av.z, av.w};
        const float b[4] = {bv.x, bv.y, bv.z, bv.w};
        #pragma unroll
        for (int i = 0; i < 4; ++i)
          #pragma unroll
          for (int j = 0; j < 4; ++j) acc[i][j] = fmaf(a[i], b[j], acc[i][j]);
      }
      __syncthreads();
    }
  }

  #pragma unroll
  for (int i = 0; i < 4; ++i) {
    const int gr = r0 + ty4 + i;
    if (gr < M) {
      #pragma unroll
      for (int j = 0; j < 4; ++j) {
        const int gc = c0 + tx4 + j;
        float v = acc[i][j] + bias[gc];
        v = fmaxf(v, 0.f);
        H[(size_t)gr * HID_C + gc] = __float2bfloat16(v);
      }
    }
  }
}

// ---------------- W2cat: [256][128], cols 0..46 = W2_l, 47..93 = W2_r, rest 0 ----------------
__global__ void build_w2cat(const float* __restrict__ Wl, const float* __restrict__ Wr,
                            float* __restrict__ Wc) {
  int idx = blockIdx.x * blockDim.x + threadIdx.x;
  if (idx < HID_C * 128) {
    int k = idx >> 7, j = idx & 127;
    float v = 0.f;
    if (j < OUT_C)           v = Wl[k * OUT_C + j];
    else if (j < 2 * OUT_C)  v = Wr[k * OUT_C + (j - OUT_C)];
    Wc[idx] = v;
  }
}

// ---------------- GEMM2: Ocat = h(bf16) @ W2cat, [M,128] f32 ----------------
__global__ __launch_bounds__(256) void gemm2(const unsigned short* __restrict__ Hm, // bf16 bits [M,256]
                                             const float* __restrict__ Bc,          // [256,128]
                                             float* __restrict__ Ocat,              // [M,128]
                                             int M) {
  __shared__ float Ats[16][68];
  __shared__ float Bs[16][64];
  const int tid = threadIdx.x;
  const int r0 = blockIdx.x * 64;
  const int c0 = blockIdx.y * 64;
  const int ty4 = (tid >> 4) * 4;
  const int tx4 = (tid & 15) * 4;

  float acc[4][4];
  #pragma unroll
  for (int i = 0; i < 4; ++i)
    #pragma unroll
    for (int j = 0; j < 4; ++j) acc[i][j] = 0.f;

  const int row_l = tid >> 2;
  const int kc    = (tid & 3) * 4;
  const int k_r   = tid >> 4;
  const int nc    = (tid & 15) * 4;

  #pragma unroll 1
  for (int kb = 0; kb < 16; ++kb) {   // K = 256
    const int gr = r0 + row_l;
    float av[4] = {0.f, 0.f, 0.f, 0.f};
    if (gr < M) {
      const ushort4 u = *(const ushort4*)&Hm[(size_t)gr * HID_C + kb * 16 + kc];
      av[0] = __uint_as_float((unsigned)u.x << 16);
      av[1] = __uint_as_float((unsigned)u.y << 16);
      av[2] = __uint_as_float((unsigned)u.z << 16);
      av[3] = __uint_as_float((unsigned)u.w << 16);
    }
    Ats[kc + 0][row_l] = av[0];
    Ats[kc + 1][row_l] = av[1];
    Ats[kc + 2][row_l] = av[2];
    Ats[kc + 3][row_l] = av[3];
    *(float4*)&Bs[k_r][nc] = *(const float4*)&Bc[(size_t)(kb * 16 + k_r) * 128 + c0 + nc];
    __syncthreads();
    #pragma unroll
    for (int kk = 0; kk < 16; ++kk) {
      const float4 av4 = *(const float4*)&Ats[kk][ty4];
      const float4 bv4 = *(const float4*)&Bs[kk][tx4];
      const float a[4] = {av4.x, av4.y, av4.z, av4.w};
      const float b[4] = {bv4.x, bv4.y, bv4.z, bv4.w};
      #pragma unroll
      for (int i = 0; i < 4; ++i)
        #pragma unroll
        for (int j = 0; j < 4; ++j) acc[i][j] = fmaf(a[i], b[j], acc[i][j]);
    }
    __syncthreads();
  }

  #pragma unroll
  for (int i = 0; i < 4; ++i) {
    const int gr = r0 + ty4 + i;
    if (gr < M) {
      float4 v; v.x = acc[i][0]; v.y = acc[i][1]; v.z = acc[i][2]; v.w = acc[i][3];
      *(float4*)&Ocat[(size_t)gr * 128 + c0 + tx4] = v;
    }
  }
}

// ---------------- final: agg2 + bias + root + log_softmax, one wave per node ----------------
__global__ __launch_bounds__(256) void final_kernel(const float* __restrict__ Ocat,
                                                    const int* __restrict__ off,
                                                    const int* __restrict__ csr,
                                                    const float* __restrict__ b2,
                                                    float* __restrict__ out, int N) {
  const int wid  = (blockIdx.x * blockDim.x + threadIdx.x) >> 6;
  const int lane = threadIdx.x & 63;
  if (wid >= N) return;
  const int s0 = off[wid], s1 = off[wid + 1];
  const bool act = lane < OUT_C;
  float sum = 0.f;
  for (int e = s0; e < s1; ++e) {
    const int s = csr[e];                                   // wave-uniform
    if (act) sum += Ocat[(size_t)s * 128 + lane];           // cols 0..46 = h@W2_l
  }
  const int deg = s1 - s0;
  const float inv = (deg > 0) ? 1.0f / (float)deg : 0.0f;
  const int cl = act ? lane : 0;                            // clamp to stay in-bounds
  float v = sum * inv + b2[cl] + Ocat[(size_t)wid * 128 + OUT_C + cl]; // cols 47..93 = h@W2_r
  if (!act) v = -INFINITY;
  float m = v;
  #pragma unroll
  for (int o = 32; o > 0; o >>= 1) m = fmaxf(m, __shfl_xor(m, o, 64));
  float ex = act ? expf(v - m) : 0.f;
  float s = ex;
  #pragma unroll
  for (int o = 32; o > 0; o >>= 1) s += __shfl_xor(s, o, 64);
  if (act) out[(size_t)wid * OUT_C + lane] = v - m - logf(s);
}

// ---------------- launch ----------------

extern "C" void kernel_launch(void* const* d_in, const int* in_sizes, int n_in,
                              void* d_out, int out_size, void* d_ws, size_t ws_size,
                              hipStream_t stream) {
  const float* x   = (const float*)d_in[0];
  const int*   ei  = (const int*)d_in[1];
  const float* W1l = (const float*)d_in[2];
  const float* b1  = (const float*)d_in[3];
  const float* W1r = (const float*)d_in[4];
  const float* W2l = (const float*)d_in[5];
  const float* b2  = (const float*)d_in[6];
  const float* W2r = (const float*)d_in[7];
  float* out = (float*)d_out;

  const int N = in_sizes[0] / IN_C;
  const int E = in_sizes[1] / 2;
  const int* src = ei;       // edge_index row 0
  const int* dst = ei + E;   // edge_index row 1

  // workspace layout (256B-aligned regions)
  char* base = (char*)d_ws;
  size_t o = 0;
  auto take = [&](size_t bytes) -> char* {
    char* p = base + o;
    o = (o + bytes + 255) & ~(size_t)255;
    return p;
  };
  int*   cnt    = (int*)take((size_t)N * 4);
  int*   cursor = (int*)take((size_t)N * 4);
  const size_t zero_bytes = o;                       // cnt + cursor (+pad)
  int*   off    = (int*)take((size_t)(N + 1) * 4);
  int*   csr    = (int*)take((size_t)E * 4);
  float* mean1  = (float*)take((size_t)N * IN_C * 4);      // 51.2 MB
  unsigned short* h = (unsigned short*)take((size_t)N * HID_C * 2); // 51.2 MB bf16
  float* w2cat  = (float*)take((size_t)HID_C * 128 * 4);
  float* Ocat   = mean1;   // alias: mean1 dead after gemm1; gemm2 runs strictly after
  (void)ws_size; (void)n_in; (void)out_size;

  hipMemsetAsync(base, 0, zero_bytes, stream);       // zero cnt + cursor

  const int tb = 256;
  count_edges<<<(E + tb - 1) / tb, tb, 0, stream>>>(dst, cnt, E);
  scan_block<<<1, 1024, 0, stream>>>(cnt, off, N);
  fill_csr<<<(E + tb - 1) / tb, tb, 0, stream>>>(src, dst, off, cursor, csr, E);
  agg1<<<(N + 3) / 4, 256, 0, stream>>>(x, off, csr, mean1, N);
  gemm1<<<dim3((N + 63) / 64, HID_C / 64), 256, 0, stream>>>(mean1, x, W1l, W1r, b1,
                                                             (__hip_bfloat16*)h, N);
  build_w2cat<<<(HID_C * 128 + tb - 1) / tb, tb, 0, stream>>>(W2l, W2r, w2cat);
  gemm2<<<dim3((N + 63) / 64, 2), 256, 0, stream>>>((const unsigned short*)h, w2cat, Ocat, N);
  final_kernel<<<(N + 3) / 4, 256, 0, stream>>>(Ocat, off, csr, b2, out, N);
}

// Round 2
// 747.006 us; speedup vs baseline: 1.3454x; 1.3454x over previous
//
#include <hip/hip_runtime.h>
#include <hip/hip_bf16.h>

constexpr int IN_C  = 128;
constexpr int HID_C = 256;
constexpr int OUT_C = 47;

typedef __attribute__((ext_vector_type(8))) short bf16x8;
typedef __attribute__((ext_vector_type(4))) float f32x4;

static __device__ __forceinline__ unsigned short f2bf(float v) {
  __hip_bfloat16 hb = __float2bfloat16(v);
  return *(unsigned short*)&hb;
}
static __device__ __forceinline__ float bf2f(unsigned short u) {
  return __uint_as_float((unsigned)u << 16);
}

// ---------------- CSR build ----------------

__global__ void count_edges(const int* __restrict__ dst, int* __restrict__ cnt, int E) {
  int e = blockIdx.x * blockDim.x + threadIdx.x;
  if (e < E) atomicAdd(&cnt[dst[e]], 1);
}

// One block, 1024 threads. Thread t owns a contiguous strip of ceil(N/1024) elems:
// strip-sum -> block scan of 1024 totals -> rewrite strip with running prefix.
__global__ __launch_bounds__(1024) void scan_all(const int* __restrict__ cnt,
                                                 int* __restrict__ off, int N) {
  __shared__ int tsum[1024];
  const int tid = threadIdx.x;
  const int C = (N + 1023) >> 10;
  const int b0 = tid * C;
  const int b1 = min(b0 + C, N);
  int s = 0;
  for (int i = b0; i < b1; ++i) s += cnt[i];
  tsum[tid] = s;
  __syncthreads();
  for (int d = 1; d < 1024; d <<= 1) {
    int t = (tid >= d) ? tsum[tid - d] : 0;
    __syncthreads();
    tsum[tid] += t;
    __syncthreads();
  }
  int run = tsum[tid] - s;   // exclusive strip base
  for (int i = b0; i < b1; ++i) { off[i] = run; run += cnt[i]; }
  if (tid == 1023) off[N] = tsum[1023];
}

__global__ void fill_csr(const int* __restrict__ src, const int* __restrict__ dst,
                         const int* __restrict__ off, int* __restrict__ cursor,
                         int* __restrict__ csr, int E) {
  int e = blockIdx.x * blockDim.x + threadIdx.x;
  if (e < E) {
    int d = dst[e];
    int p = atomicAdd(&cursor[d], 1);
    csr[off[d] + p] = src[e];
  }
}

// ---------------- fp32 -> bf16 convert (x) ----------------
__global__ void f32_to_bf16(const float* __restrict__ in, unsigned short* __restrict__ out, int n4) {
  int i = blockIdx.x * blockDim.x + threadIdx.x;
  if (i < n4) {
    float4 v = *(const float4*)&in[i * 4];
    ushort4 o;
    o.x = f2bf(v.x); o.y = f2bf(v.y); o.z = f2bf(v.z); o.w = f2bf(v.w);
    *(ushort4*)&out[i * 4] = o;
  }
}

// ---------------- layer-1 aggregation (bf16 x, bf16 mean out) ----------------
// One wave per dst node; lane owns 2 channels (one uint = 2 bf16). 256B/edge.
__global__ __launch_bounds__(256) void agg1(const unsigned short* __restrict__ xb,
                                            const int* __restrict__ off,
                                            const int* __restrict__ csr,
                                            unsigned short* __restrict__ meanb, int N) {
  const int wid  = (blockIdx.x * blockDim.x + threadIdx.x) >> 6;
  const int lane = threadIdx.x & 63;
  if (wid >= N) return;
  const unsigned* xw = (const unsigned*)xb;       // row = 64 uints
  const int s0 = off[wid], s1 = off[wid + 1];
  float a0 = 0.f, a1 = 0.f, c0 = 0.f, c1 = 0.f;
  int e = s0;
  for (; e + 2 <= s1; e += 2) {
    const int sA = csr[e], sB = csr[e + 1];
    const unsigned uA = xw[(size_t)sA * 64 + lane];
    const unsigned uB = xw[(size_t)sB * 64 + lane];
    a0 += __uint_as_float(uA << 16); a1 += __uint_as_float(uA & 0xffff0000u);
    c0 += __uint_as_float(uB << 16); c1 += __uint_as_float(uB & 0xffff0000u);
  }
  if (e < s1) {
    const int sA = csr[e];
    const unsigned uA = xw[(size_t)sA * 64 + lane];
    a0 += __uint_as_float(uA << 16); a1 += __uint_as_float(uA & 0xffff0000u);
  }
  a0 += c0; a1 += c1;
  const int deg = s1 - s0;
  const float inv = (deg > 0) ? 1.0f / (float)deg : 0.0f;
  const unsigned lo = f2bf(a0 * inv), hi = f2bf(a1 * inv);
  ((unsigned*)meanb)[(size_t)wid * 64 + lane] = lo | (hi << 16);
}

// ---------------- weight prep: transposed bf16 concatenated weights ----------------
// W1cat_T [256][256]: row j (out col), col k: k<128 -> W1_l[k][j], else W1_r[k-128][j]
__global__ void build_w1cat_t(const float* __restrict__ Wl, const float* __restrict__ Wr,
                              unsigned short* __restrict__ BT) {
  int idx = blockIdx.x * blockDim.x + threadIdx.x;
  if (idx < 256 * 256) {
    int j = idx >> 8, k = idx & 255;
    float v = (k < 128) ? Wl[k * 256 + j] : Wr[(k - 128) * 256 + j];
    BT[idx] = f2bf(v);
  }
}
// W2cat_T [128][256]: row j: j<47 -> W2_l[k][j], j<94 -> W2_r[k][j-47], else 0
__global__ void build_w2cat_t(const float* __restrict__ Wl, const float* __restrict__ Wr,
                              unsigned short* __restrict__ BT) {
  int idx = blockIdx.x * blockDim.x + threadIdx.x;
  if (idx < 128 * 256) {
    int j = idx >> 8, k = idx & 255;
    float v = 0.f;
    if (j < OUT_C)           v = Wl[k * OUT_C + j];
    else if (j < 2 * OUT_C)  v = Wr[k * OUT_C + (j - OUT_C)];
    BT[idx] = f2bf(v);
  }
}

// ---------------- MFMA GEMM: C[M,ONC] = A[M,256] @ BT[ONC,256]^T (bf16 in, bf16 out) ----------------
// 128x128 tile, BK=64, 256 threads = 4 waves (2x2), 4x4 fragments of 16x16x32 per wave.
// LDS tiles [128][64] bf16, linear dest for global_load_lds; T2 XOR swizzle via
// pre-swizzled global source chunk + swizzled ds_read (rule #21).
// MODE 0 (gemm1): A = [mean|x] (two [M,128] sources), +bias, ReLU.  MODE 1 (gemm2): A = h [M,256].
template<int MODE>
__global__ __launch_bounds__(256) void gemm_mfma(const unsigned short* __restrict__ A0,
                                                 const unsigned short* __restrict__ A1,
                                                 const unsigned short* __restrict__ BT,
                                                 const float* __restrict__ bias,
                                                 unsigned short* __restrict__ Out,
                                                 int M) {
  constexpr int ONC = (MODE == 0) ? 256 : 128;
  __shared__ unsigned short Asl[128 * 64];
  __shared__ unsigned short Bsl[128 * 64];
  const int tid  = threadIdx.x;
  const int wid  = tid >> 6, lane = tid & 63;
  const int wm   = wid >> 1, wn = wid & 1;
  const int r0   = blockIdx.x * 128;
  const int c0   = blockIdx.y * 128;

  f32x4 acc[4][4];
  #pragma unroll
  for (int m = 0; m < 4; ++m)
    #pragma unroll
    for (int n = 0; n < 4; ++n)
      #pragma unroll
      for (int j = 0; j < 4; ++j) acc[m][n][j] = 0.f;

  const int srow = lane >> 3;              // staging row within 8-row group
  const int cs   = (lane & 7) ^ srow;      // pre-swizzled 16B source chunk
  const int fr   = lane & 15;              // fragment row/col
  const int klo  = (lane >> 4) * 16;       // fragment k-chunk byte offset
  const int swz  = (fr & 7) << 4;          // read-side XOR

  #pragma unroll 1
  for (int kb = 0; kb < 4; ++kb) {
    const unsigned short* Ap;
    int acol, ak;
    if (MODE == 0) { Ap = (kb < 2) ? A0 : A1; acol = (kb & 1) * 64; ak = 128; }
    else           { Ap = A0;                 acol = kb * 64;       ak = 256; }
    #pragma unroll
    for (int i = 0; i < 4; ++i) {
      const int rl = wid * 32 + i * 8 + srow;          // tile row 0..127
      int gr = r0 + rl; if (gr > M - 1) gr = M - 1;    // clamp (dup rows discarded on store)
      const unsigned short* gsa = Ap + (size_t)gr * ak + acol + cs * 8;
      __builtin_amdgcn_global_load_lds(
          (const __attribute__((address_space(1))) unsigned int*)gsa,
          (__attribute__((address_space(3))) unsigned int*)&Asl[(wid * 32 + i * 8) * 64],
          16, 0, 0);
      const unsigned short* gsb = BT + (size_t)(c0 + rl) * 256 + kb * 64 + cs * 8;
      __builtin_amdgcn_global_load_lds(
          (const __attribute__((address_space(1))) unsigned int*)gsb,
          (__attribute__((address_space(3))) unsigned int*)&Bsl[(wid * 32 + i * 8) * 64],
          16, 0, 0);
    }
    asm volatile("s_waitcnt vmcnt(0)");
    __syncthreads();
    #pragma unroll
    for (int ks = 0; ks < 2; ++ks) {
      bf16x8 af[4], bfv[4];
      #pragma unroll
      for (int m = 0; m < 4; ++m) {
        const int ro = (wm * 64 + m * 16 + fr) * 128 + ((ks * 64 + klo) ^ swz);
        af[m] = *(const bf16x8*)((const char*)Asl + ro);
      }
      #pragma unroll
      for (int n = 0; n < 4; ++n) {
        const int ro = (wn * 64 + n * 16 + fr) * 128 + ((ks * 64 + klo) ^ swz);
        bfv[n] = *(const bf16x8*)((const char*)Bsl + ro);
      }
      #pragma unroll
      for (int m = 0; m < 4; ++m)
        #pragma unroll
        for (int n = 0; n < 4; ++n)
          acc[m][n] = __builtin_amdgcn_mfma_f32_16x16x32_bf16(af[m], bfv[n], acc[m][n], 0, 0, 0);
    }
    __syncthreads();
  }

  // epilogue: C/D layout col=lane&15, row=(lane>>4)*4+reg
  const int orow0 = r0 + wm * 64 + (lane >> 4) * 4;
  const int ocol0 = c0 + wn * 64 + (lane & 15);
  #pragma unroll
  for (int m = 0; m < 4; ++m) {
    #pragma unroll
    for (int n = 0; n < 4; ++n) {
      const int col = ocol0 + n * 16;
      const float badd = (MODE == 0) ? bias[col] : 0.f;
      #pragma unroll
      for (int j = 0; j < 4; ++j) {
        const int row = orow0 + m * 16 + j;
        if (row < M) {
          float v = acc[m][n][j] + badd;
          if (MODE == 0) v = fmaxf(v, 0.f);
          Out[(size_t)row * ONC + col] = f2bf(v);
        }
      }
    }
  }
}

// ---------------- final: agg2 + bias + root + log_softmax ----------------
__global__ __launch_bounds__(256) void final_kernel(const unsigned short* __restrict__ Ob,
                                                    const int* __restrict__ off,
                                                    const int* __restrict__ csr,
                                                    const float* __restrict__ b2,
                                                    float* __restrict__ out, int N) {
  const int wid  = (blockIdx.x * blockDim.x + threadIdx.x) >> 6;
  const int lane = threadIdx.x & 63;
  if (wid >= N) return;
  const int s0 = off[wid], s1 = off[wid + 1];
  const bool act = lane < OUT_C;
  const int cl = act ? lane : 0;
  float sum = 0.f;
  for (int e = s0; e < s1; ++e) {
    const int s = csr[e];                               // wave-uniform
    sum += bf2f(Ob[(size_t)s * 128 + cl]);
  }
  const int deg = s1 - s0;
  const float inv = (deg > 0) ? 1.0f / (float)deg : 0.0f;
  float v = sum * inv + b2[cl] + bf2f(Ob[(size_t)wid * 128 + OUT_C + cl]);
  if (!act) v = -INFINITY;
  float m = v;
  #pragma unroll
  for (int o = 32; o > 0; o >>= 1) m = fmaxf(m, __shfl_xor(m, o, 64));
  float ex = act ? expf(v - m) : 0.f;
  float s = ex;
  #pragma unroll
  for (int o = 32; o > 0; o >>= 1) s += __shfl_xor(s, o, 64);
  if (act) out[(size_t)wid * OUT_C + lane] = v - m - logf(s);
}

// ---------------- launch ----------------

extern "C" void kernel_launch(void* const* d_in, const int* in_sizes, int n_in,
                              void* d_out, int out_size, void* d_ws, size_t ws_size,
                              hipStream_t stream) {
  const float* x   = (const float*)d_in[0];
  const int*   ei  = (const int*)d_in[1];
  const float* W1l = (const float*)d_in[2];
  const float* b1  = (const float*)d_in[3];
  const float* W1r = (const float*)d_in[4];
  const float* W2l = (const float*)d_in[5];
  const float* b2  = (const float*)d_in[6];
  const float* W2r = (const float*)d_in[7];
  float* out = (float*)d_out;

  const int N = in_sizes[0] / IN_C;
  const int E = in_sizes[1] / 2;
  const int* src = ei;
  const int* dst = ei + E;

  char* base = (char*)d_ws;
  size_t o = 0;
  auto take = [&](size_t bytes) -> char* {
    char* p = base + o;
    o = (o + bytes + 255) & ~(size_t)255;
    return p;
  };
  int* cnt    = (int*)take((size_t)N * 4);
  int* cursor = (int*)take((size_t)N * 4);
  const size_t zero_bytes = o;
  int* off    = (int*)take((size_t)(N + 1) * 4);
  int* csr    = (int*)take((size_t)E * 4);
  unsigned short* xb    = (unsigned short*)take((size_t)N * IN_C * 2);   // 25.6 MB
  unsigned short* meanb = (unsigned short*)take((size_t)N * IN_C * 2);   // 25.6 MB
  unsigned short* h     = (unsigned short*)take((size_t)N * HID_C * 2);  // 51.2 MB
  unsigned short* W1T   = (unsigned short*)take((size_t)256 * 256 * 2);
  unsigned short* W2T   = (unsigned short*)take((size_t)128 * 256 * 2);
  unsigned short* Ocat  = meanb;   // alias: meanb dead after gemm1
  (void)ws_size; (void)n_in; (void)out_size;

  hipMemsetAsync(base, 0, zero_bytes, stream);

  const int tb = 256;
  count_edges<<<(E + tb - 1) / tb, tb, 0, stream>>>(dst, cnt, E);
  scan_all<<<1, 1024, 0, stream>>>(cnt, off, N);
  fill_csr<<<(E + tb - 1) / tb, tb, 0, stream>>>(src, dst, off, cursor, csr, E);

  const int n4 = N * IN_C / 4;
  f32_to_bf16<<<(n4 + tb - 1) / tb, tb, 0, stream>>>(x, xb, n4);
  build_w1cat_t<<<256, 256, 0, stream>>>(W1l, W1r, W1T);
  build_w2cat_t<<<128, 256, 0, stream>>>(W2l, W2r, W2T);

  agg1<<<(N + 3) / 4, 256, 0, stream>>>(xb, off, csr, meanb, N);

  const int mb = (N + 127) / 128;
  gemm_mfma<0><<<dim3(mb, 2), 256, 0, stream>>>(meanb, xb, W1T, b1, h, N);
  gemm_mfma<1><<<dim3(mb, 1), 256, 0, stream>>>(h, nullptr, W2T, nullptr, Ocat, N);

  final_kernel<<<(N + 3) / 4, 256, 0, stream>>>(Ocat, off, csr, b2, out, N);
}

// Round 7
// 604.525 us; speedup vs baseline: 1.6625x; 1.2357x over previous
//
#include <hip/hip_runtime.h>
#include <hip/hip_bf16.h>

constexpr int IN_C  = 128;
constexpr int HID_C = 256;
constexpr int OUT_C = 47;

typedef __attribute__((ext_vector_type(8))) short bf16x8;
typedef __attribute__((ext_vector_type(4))) float f32x4;

static __device__ __forceinline__ unsigned short f2bf(float v) {
  __hip_bfloat16 hb = __float2bfloat16(v);
  return *(unsigned short*)&hb;
}
static __device__ __forceinline__ float bf2f(unsigned short u) {
  return __uint_as_float((unsigned)u << 16);
}

// ---------------- CSR build ----------------

__global__ void count_edges(const int* __restrict__ dst, int* __restrict__ cnt, int E) {
  int e = blockIdx.x * blockDim.x + threadIdx.x;
  if (e < E) atomicAdd(&cnt[dst[e]], 1);
}

// 3-phase parallel scan: partials -> roots -> write. 1024 elems per block.
__global__ __launch_bounds__(256) void scan_partials(const int* __restrict__ cnt,
                                                     int* __restrict__ part, int N) {
  const int i0 = blockIdx.x * 1024 + threadIdx.x * 4;
  int s = 0;
  if (i0 + 3 < N) {
    const int4 v = *(const int4*)&cnt[i0];
    s = v.x + v.y + v.z + v.w;
  } else {
    for (int k = 0; k < 4; ++k) { const int i = i0 + k; if (i < N) s += cnt[i]; }
  }
  #pragma unroll
  for (int o = 32; o > 0; o >>= 1) s += __shfl_xor(s, o, 64);
  __shared__ int ws[4];
  if ((threadIdx.x & 63) == 0) ws[threadIdx.x >> 6] = s;
  __syncthreads();
  if (threadIdx.x == 0) part[blockIdx.x] = ws[0] + ws[1] + ws[2] + ws[3];
}

// One block scans <=1024 partials in place (inclusive->exclusive), writes off[N]=total.
__global__ __launch_bounds__(1024) void scan_roots(int* __restrict__ part,
                                                   int* __restrict__ off, int nb, int N) {
  __shared__ int tmp[1024];
  const int t = threadIdx.x;
  const int v = (t < nb) ? part[t] : 0;
  tmp[t] = v;
  __syncthreads();
  for (int d = 1; d < 1024; d <<= 1) {
    const int u = (t >= d) ? tmp[t - d] : 0;
    __syncthreads();
    tmp[t] += u;
    __syncthreads();
  }
  if (t < nb) part[t] = tmp[t] - v;        // exclusive root per block
  if (t == 1023) off[N] = tmp[1023];       // grand total
}

__global__ __launch_bounds__(256) void scan_write(const int* __restrict__ cnt,
                                                  const int* __restrict__ part,
                                                  int* __restrict__ off, int N) {
  const int b = blockIdx.x;
  const int i0 = b * 1024 + threadIdx.x * 4;
  int4 v = make_int4(0, 0, 0, 0);
  if (i0 + 3 < N) v = *(const int4*)&cnt[i0];
  else {
    int* p = (int*)&v;
    for (int k = 0; k < 4; ++k) { const int i = i0 + k; if (i < N) p[k] = cnt[i]; }
  }
  const int tsum = v.x + v.y + v.z + v.w;
  const int lane = threadIdx.x & 63;
  int incl = tsum;
  #pragma unroll
  for (int o = 1; o < 64; o <<= 1) {
    const int u = __shfl_up(incl, o, 64);
    if (lane >= o) incl += u;
  }
  __shared__ int wsum[4];
  const int wv = threadIdx.x >> 6;
  if (lane == 63) wsum[wv] = incl;
  __syncthreads();
  int wbase = 0;
  for (int w = 0; w < wv; ++w) wbase += wsum[w];
  const int tbase = part[b] + wbase + incl - tsum;   // exclusive for this thread
  int4 ov;
  ov.x = tbase;
  ov.y = tbase + v.x;
  ov.z = tbase + v.x + v.y;
  ov.w = tbase + v.x + v.y + v.z;
  if (i0 + 3 < N) *(int4*)&off[i0] = ov;
  else {
    int* p = (int*)&ov;
    for (int k = 0; k < 4; ++k) { const int i = i0 + k; if (i < N) off[i] = p[k]; }
  }
}

__global__ void fill_csr(const int* __restrict__ src, const int* __restrict__ dst,
                         const int* __restrict__ off, int* __restrict__ cursor,
                         int* __restrict__ csr, int E) {
  int e = blockIdx.x * blockDim.x + threadIdx.x;
  if (e < E) {
    int d = dst[e];
    int p = atomicAdd(&cursor[d], 1);
    csr[off[d] + p] = src[e];
  }
}

// ---------------- fp32 -> bf16 convert (x) ----------------
__global__ void f32_to_bf16(const float* __restrict__ in, unsigned short* __restrict__ out, int n4) {
  int i = blockIdx.x * blockDim.x + threadIdx.x;
  if (i < n4) {
    float4 v = *(const float4*)&in[i * 4];
    ushort4 o;
    o.x = f2bf(v.x); o.y = f2bf(v.y); o.z = f2bf(v.z); o.w = f2bf(v.w);
    *(ushort4*)&out[i * 4] = o;
  }
}

// ---------------- layer-1 aggregation (bf16 x, bf16 mean out) ----------------
// One wave per dst node; lane owns 2 channels (one uint = 2 bf16). 256B/edge.
__global__ __launch_bounds__(256) void agg1(const unsigned short* __restrict__ xb,
                                            const int* __restrict__ off,
                                            const int* __restrict__ csr,
                                            unsigned short* __restrict__ meanb, int N) {
  const int wid  = (blockIdx.x * blockDim.x + threadIdx.x) >> 6;
  const int lane = threadIdx.x & 63;
  if (wid >= N) return;
  const unsigned* xw = (const unsigned*)xb;       // row = 64 uints
  const int s0 = off[wid], s1 = off[wid + 1];
  float a0 = 0.f, a1 = 0.f, c0 = 0.f, c1 = 0.f;
  int e = s0;
  for (; e + 2 <= s1; e += 2) {
    const int sA = csr[e], sB = csr[e + 1];
    const unsigned uA = xw[(size_t)sA * 64 + lane];
    const unsigned uB = xw[(size_t)sB * 64 + lane];
    a0 += __uint_as_float(uA << 16); a1 += __uint_as_float(uA & 0xffff0000u);
    c0 += __uint_as_float(uB << 16); c1 += __uint_as_float(uB & 0xffff0000u);
  }
  if (e < s1) {
    const int sA = csr[e];
    const unsigned uA = xw[(size_t)sA * 64 + lane];
    a0 += __uint_as_float(uA << 16); a1 += __uint_as_float(uA & 0xffff0000u);
  }
  a0 += c0; a1 += c1;
  const int deg = s1 - s0;
  const float inv = (deg > 0) ? 1.0f / (float)deg : 0.0f;
  const unsigned lo = f2bf(a0 * inv), hi = f2bf(a1 * inv);
  ((unsigned*)meanb)[(size_t)wid * 64 + lane] = lo | (hi << 16);
}

// ---------------- weight prep: transposed bf16 concatenated weights ----------------
__global__ void build_w1cat_t(const float* __restrict__ Wl, const float* __restrict__ Wr,
                              unsigned short* __restrict__ BT) {
  int idx = blockIdx.x * blockDim.x + threadIdx.x;
  if (idx < 256 * 256) {
    int j = idx >> 8, k = idx & 255;
    float v = (k < 128) ? Wl[k * 256 + j] : Wr[(k - 128) * 256 + j];
    BT[idx] = f2bf(v);
  }
}
__global__ void build_w2cat_t(const float* __restrict__ Wl, const float* __restrict__ Wr,
                              unsigned short* __restrict__ BT) {
  int idx = blockIdx.x * blockDim.x + threadIdx.x;
  if (idx < 128 * 256) {
    int j = idx >> 8, k = idx & 255;
    float v = 0.f;
    if (j < OUT_C)           v = Wl[k * OUT_C + j];
    else if (j < 2 * OUT_C)  v = Wr[k * OUT_C + (j - OUT_C)];
    BT[idx] = f2bf(v);
  }
}

// ---------------- MFMA GEMM: C[M,ONC] = A[M,256] @ BT[ONC,256]^T (bf16 in, bf16 out) ----------------
template<int MODE>
__global__ __launch_bounds__(256) void gemm_mfma(const unsigned short* __restrict__ A0,
                                                 const unsigned short* __restrict__ A1,
                                                 const unsigned short* __restrict__ BT,
                                                 const float* __restrict__ bias,
                                                 unsigned short* __restrict__ Out,
                                                 int M) {
  constexpr int ONC = (MODE == 0) ? 256 : 128;
  __shared__ unsigned short Asl[128 * 64];
  __shared__ unsigned short Bsl[128 * 64];
  const int tid  = threadIdx.x;
  const int wid  = tid >> 6, lane = tid & 63;
  const int wm   = wid >> 1, wn = wid & 1;
  const int r0   = blockIdx.x * 128;
  const int c0   = blockIdx.y * 128;

  f32x4 acc[4][4];
  #pragma unroll
  for (int m = 0; m < 4; ++m)
    #pragma unroll
    for (int n = 0; n < 4; ++n)
      #pragma unroll
      for (int j = 0; j < 4; ++j) acc[m][n][j] = 0.f;

  const int srow = lane >> 3;
  const int cs   = (lane & 7) ^ srow;
  const int fr   = lane & 15;
  const int klo  = (lane >> 4) * 16;
  const int swz  = (fr & 7) << 4;

  #pragma unroll 1
  for (int kb = 0; kb < 4; ++kb) {
    const unsigned short* Ap;
    int acol, ak;
    if (MODE == 0) { Ap = (kb < 2) ? A0 : A1; acol = (kb & 1) * 64; ak = 128; }
    else           { Ap = A0;                 acol = kb * 64;       ak = 256; }
    #pragma unroll
    for (int i = 0; i < 4; ++i) {
      const int rl = wid * 32 + i * 8 + srow;
      int gr = r0 + rl; if (gr > M - 1) gr = M - 1;
      const unsigned short* gsa = Ap + (size_t)gr * ak + acol + cs * 8;
      __builtin_amdgcn_global_load_lds(
          (const __attribute__((address_space(1))) unsigned int*)gsa,
          (__attribute__((address_space(3))) unsigned int*)&Asl[(wid * 32 + i * 8) * 64],
          16, 0, 0);
      const unsigned short* gsb = BT + (size_t)(c0 + rl) * 256 + kb * 64 + cs * 8;
      __builtin_amdgcn_global_load_lds(
          (const __attribute__((address_space(1))) unsigned int*)gsb,
          (__attribute__((address_space(3))) unsigned int*)&Bsl[(wid * 32 + i * 8) * 64],
          16, 0, 0);
    }
    asm volatile("s_waitcnt vmcnt(0)");
    __syncthreads();
    #pragma unroll
    for (int ks = 0; ks < 2; ++ks) {
      bf16x8 af[4], bfv[4];
      #pragma unroll
      for (int m = 0; m < 4; ++m) {
        const int ro = (wm * 64 + m * 16 + fr) * 128 + ((ks * 64 + klo) ^ swz);
        af[m] = *(const bf16x8*)((const char*)Asl + ro);
      }
      #pragma unroll
      for (int n = 0; n < 4; ++n) {
        const int ro = (wn * 64 + n * 16 + fr) * 128 + ((ks * 64 + klo) ^ swz);
        bfv[n] = *(const bf16x8*)((const char*)Bsl + ro);
      }
      #pragma unroll
      for (int m = 0; m < 4; ++m)
        #pragma unroll
        for (int n = 0; n < 4; ++n)
          acc[m][n] = __builtin_amdgcn_mfma_f32_16x16x32_bf16(af[m], bfv[n], acc[m][n], 0, 0, 0);
    }
    __syncthreads();
  }

  const int orow0 = r0 + wm * 64 + (lane >> 4) * 4;
  const int ocol0 = c0 + wn * 64 + (lane & 15);
  #pragma unroll
  for (int m = 0; m < 4; ++m) {
    #pragma unroll
    for (int n = 0; n < 4; ++n) {
      const int col = ocol0 + n * 16;
      const float badd = (MODE == 0) ? bias[col] : 0.f;
      #pragma unroll
      for (int j = 0; j < 4; ++j) {
        const int row = orow0 + m * 16 + j;
        if (row < M) {
          float v = acc[m][n][j] + badd;
          if (MODE == 0) v = fmaxf(v, 0.f);
          Out[(size_t)row * ONC + col] = f2bf(v);
        }
      }
    }
  }
}

// ---------------- final: agg2 + bias + root + log_softmax ----------------
__global__ __launch_bounds__(256) void final_kernel(const unsigned short* __restrict__ Ob,
                                                    const int* __restrict__ off,
                                                    const int* __restrict__ csr,
                                                    const float* __restrict__ b2,
                                                    float* __restrict__ out, int N) {
  const int wid  = (blockIdx.x * blockDim.x + threadIdx.x) >> 6;
  const int lane = threadIdx.x & 63;
  if (wid >= N) return;
  const int s0 = off[wid], s1 = off[wid + 1];
  const bool act = lane < OUT_C;
  const int cl = act ? lane : 0;
  float sum = 0.f;
  for (int e = s0; e < s1; ++e) {
    const int s = csr[e];                               // wave-uniform
    sum += bf2f(Ob[(size_t)s * 128 + cl]);
  }
  const int deg = s1 - s0;
  const float inv = (deg > 0) ? 1.0f / (float)deg : 0.0f;
  float v = sum * inv + b2[cl] + bf2f(Ob[(size_t)wid * 128 + OUT_C + cl]);
  if (!act) v = -INFINITY;
  float m = v;
  #pragma unroll
  for (int o = 32; o > 0; o >>= 1) m = fmaxf(m, __shfl_xor(m, o, 64));
  float ex = act ? expf(v - m) : 0.f;
  float s = ex;
  #pragma unroll
  for (int o = 32; o > 0; o >>= 1) s += __shfl_xor(s, o, 64);
  if (act) out[(size_t)wid * OUT_C + lane] = v - m - logf(s);
}

// ---------------- launch ----------------

extern "C" void kernel_launch(void* const* d_in, const int* in_sizes, int n_in,
                              void* d_out, int out_size, void* d_ws, size_t ws_size,
                              hipStream_t stream) {
  const float* x   = (const float*)d_in[0];
  const int*   ei  = (const int*)d_in[1];
  const float* W1l = (const float*)d_in[2];
  const float* b1  = (const float*)d_in[3];
  const float* W1r = (const float*)d_in[4];
  const float* W2l = (const float*)d_in[5];
  const float* b2  = (const float*)d_in[6];
  const float* W2r = (const float*)d_in[7];
  float* out = (float*)d_out;

  const int N = in_sizes[0] / IN_C;
  const int E = in_sizes[1] / 2;
  const int* src = ei;
  const int* dst = ei + E;

  char* base = (char*)d_ws;
  size_t o = 0;
  auto take = [&](size_t bytes) -> char* {
    char* p = base + o;
    o = (o + bytes + 255) & ~(size_t)255;
    return p;
  };
  int* cnt    = (int*)take((size_t)N * 4);
  int* cursor = (int*)take((size_t)N * 4);
  const size_t zero_bytes = o;
  int* off    = (int*)take((size_t)(N + 1) * 4);
  int* part   = (int*)take((size_t)1024 * 4);
  int* csr    = (int*)take((size_t)E * 4);
  unsigned short* xb    = (unsigned short*)take((size_t)N * IN_C * 2);
  unsigned short* meanb = (unsigned short*)take((size_t)N * IN_C * 2);
  unsigned short* h     = (unsigned short*)take((size_t)N * HID_C * 2);
  unsigned short* W1T   = (unsigned short*)take((size_t)256 * 256 * 2);
  unsigned short* W2T   = (unsigned short*)take((size_t)128 * 256 * 2);
  unsigned short* Ocat  = meanb;   // alias: meanb dead after gemm1
  (void)ws_size; (void)n_in; (void)out_size;

  hipMemsetAsync(base, 0, zero_bytes, stream);

  const int tb = 256;
  const int nb = (N + 1023) / 1024;
  count_edges<<<(E + tb - 1) / tb, tb, 0, stream>>>(dst, cnt, E);
  scan_partials<<<nb, 256, 0, stream>>>(cnt, part, N);
  scan_roots<<<1, 1024, 0, stream>>>(part, off, nb, N);
  scan_write<<<nb, 256, 0, stream>>>(cnt, part, off, N);
  fill_csr<<<(E + tb - 1) / tb, tb, 0, stream>>>(src, dst, off, cursor, csr, E);

  const int n4 = N * IN_C / 4;
  f32_to_bf16<<<(n4 + tb - 1) / tb, tb, 0, stream>>>(x, xb, n4);
  build_w1cat_t<<<256, 256, 0, stream>>>(W1l, W1r, W1T);
  build_w2cat_t<<<128, 256, 0, stream>>>(W2l, W2r, W2T);

  agg1<<<(N + 3) / 4, 256, 0, stream>>>(xb, off, csr, meanb, N);

  const int mb = (N + 127) / 128;
  gemm_mfma<0><<<dim3(mb, 2), 256, 0, stream>>>(meanb, xb, W1T, b1, h, N);
  gemm_mfma<1><<<dim3(mb, 1), 256, 0, stream>>>(h, nullptr, W2T, nullptr, Ocat, N);

  final_kernel<<<(N + 3) / 4, 256, 0, stream>>>(Ocat, off, csr, b2, out, N);
}

// Round 8
// 475.699 us; speedup vs baseline: 2.1127x; 1.2708x over previous
//
#include <hip/hip_runtime.h>
#include <hip/hip_bf16.h>

constexpr int IN_C  = 128;
constexpr int HID_C = 256;
constexpr int OUT_C = 47;

typedef __attribute__((ext_vector_type(8))) short bf16x8;
typedef __attribute__((ext_vector_type(4))) float f32x4;

static __device__ __forceinline__ unsigned short f2bf(float v) {
  __hip_bfloat16 hb = __float2bfloat16(v);
  return *(unsigned short*)&hb;
}
static __device__ __forceinline__ float bf2f(unsigned short u) {
  return __uint_as_float((unsigned)u << 16);
}

// ---------------- CSR build ----------------

__global__ void count_edges(const int* __restrict__ dst, int* __restrict__ cnt, int E) {
  int e = blockIdx.x * blockDim.x + threadIdx.x;
  if (e < E) atomicAdd(&cnt[dst[e]], 1);
}

// 3-phase parallel scan: partials -> roots -> write. 1024 elems per block.
__global__ __launch_bounds__(256) void scan_partials(const int* __restrict__ cnt,
                                                     int* __restrict__ part, int N) {
  const int i0 = blockIdx.x * 1024 + threadIdx.x * 4;
  int s = 0;
  if (i0 + 3 < N) {
    const int4 v = *(const int4*)&cnt[i0];
    s = v.x + v.y + v.z + v.w;
  } else {
    for (int k = 0; k < 4; ++k) { const int i = i0 + k; if (i < N) s += cnt[i]; }
  }
  #pragma unroll
  for (int o = 32; o > 0; o >>= 1) s += __shfl_xor(s, o, 64);
  __shared__ int ws[4];
  if ((threadIdx.x & 63) == 0) ws[threadIdx.x >> 6] = s;
  __syncthreads();
  if (threadIdx.x == 0) part[blockIdx.x] = ws[0] + ws[1] + ws[2] + ws[3];
}

// One block scans <=1024 partials in place (inclusive->exclusive), writes off[N]=total.
__global__ __launch_bounds__(1024) void scan_roots(int* __restrict__ part,
                                                   int* __restrict__ off, int nb, int N) {
  __shared__ int tmp[1024];
  const int t = threadIdx.x;
  const int v = (t < nb) ? part[t] : 0;
  tmp[t] = v;
  __syncthreads();
  for (int d = 1; d < 1024; d <<= 1) {
    const int u = (t >= d) ? tmp[t - d] : 0;
    __syncthreads();
    tmp[t] += u;
    __syncthreads();
  }
  if (t < nb) part[t] = tmp[t] - v;        // exclusive root per block
  if (t == 1023) off[N] = tmp[1023];       // grand total
}

__global__ __launch_bounds__(256) void scan_write(const int* __restrict__ cnt,
                                                  const int* __restrict__ part,
                                                  int* __restrict__ off, int N) {
  const int b = blockIdx.x;
  const int i0 = b * 1024 + threadIdx.x * 4;
  int4 v = make_int4(0, 0, 0, 0);
  if (i0 + 3 < N) v = *(const int4*)&cnt[i0];
  else {
    int* p = (int*)&v;
    for (int k = 0; k < 4; ++k) { const int i = i0 + k; if (i < N) p[k] = cnt[i]; }
  }
  const int tsum = v.x + v.y + v.z + v.w;
  const int lane = threadIdx.x & 63;
  int incl = tsum;
  #pragma unroll
  for (int o = 1; o < 64; o <<= 1) {
    const int u = __shfl_up(incl, o, 64);
    if (lane >= o) incl += u;
  }
  __shared__ int wsum[4];
  const int wv = threadIdx.x >> 6;
  if (lane == 63) wsum[wv] = incl;
  __syncthreads();
  int wbase = 0;
  for (int w = 0; w < wv; ++w) wbase += wsum[w];
  const int tbase = part[b] + wbase + incl - tsum;   // exclusive for this thread
  int4 ov;
  ov.x = tbase;
  ov.y = tbase + v.x;
  ov.z = tbase + v.x + v.y;
  ov.w = tbase + v.x + v.y + v.z;
  if (i0 + 3 < N) *(int4*)&off[i0] = ov;
  else {
    int* p = (int*)&ov;
    for (int k = 0; k < 4; ++k) { const int i = i0 + k; if (i < N) off[i] = p[k]; }
  }
}

__global__ void fill_csr(const int* __restrict__ src, const int* __restrict__ dst,
                         const int* __restrict__ off, int* __restrict__ cursor,
                         int* __restrict__ csr, int E) {
  int e = blockIdx.x * blockDim.x + threadIdx.x;
  if (e < E) {
    int d = dst[e];
    int p = atomicAdd(&cursor[d], 1);
    csr[off[d] + p] = src[e];
  }
}

// ---------------- fp32 -> bf16 convert (x) ----------------
__global__ void f32_to_bf16(const float* __restrict__ in, unsigned short* __restrict__ out, int n4) {
  int i = blockIdx.x * blockDim.x + threadIdx.x;
  if (i < n4) {
    float4 v = *(const float4*)&in[i * 4];
    ushort4 o;
    o.x = f2bf(v.x); o.y = f2bf(v.y); o.z = f2bf(v.z); o.w = f2bf(v.w);
    *(ushort4*)&out[i * 4] = o;
  }
}

// ---------------- layer-1 aggregation (bf16 x, bf16 mean out) ----------------
// One wave per dst node. Edge indices bulk-loaded coalesced (64/chunk) then
// shfl-broadcast; 4-edge unroll with 4 accumulator pairs for MLP.
__global__ __launch_bounds__(256) void agg1(const unsigned short* __restrict__ xb,
                                            const int* __restrict__ off,
                                            const int* __restrict__ csr,
                                            unsigned short* __restrict__ meanb, int N) {
  const int wid  = (blockIdx.x * blockDim.x + threadIdx.x) >> 6;
  const int lane = threadIdx.x & 63;
  if (wid >= N) return;
  const unsigned* xw = (const unsigned*)xb;       // row = 64 uints
  const int s0 = off[wid], s1 = off[wid + 1];
  float a0 = 0.f, a1 = 0.f, b0 = 0.f, b1 = 0.f;
  float c0 = 0.f, c1 = 0.f, d0 = 0.f, d1 = 0.f;
  for (int base = s0; base < s1; base += 64) {
    const int cnt = min(64, s1 - base);
    const int idx = (lane < cnt) ? csr[base + lane] : 0;   // coalesced bulk index load
    int e = 0;
    for (; e + 4 <= cnt; e += 4) {
      const int sA = __shfl(idx, e, 64),     sB = __shfl(idx, e + 1, 64);
      const int sC = __shfl(idx, e + 2, 64), sD = __shfl(idx, e + 3, 64);
      const unsigned uA = xw[(size_t)sA * 64 + lane];
      const unsigned uB = xw[(size_t)sB * 64 + lane];
      const unsigned uC = xw[(size_t)sC * 64 + lane];
      const unsigned uD = xw[(size_t)sD * 64 + lane];
      a0 += __uint_as_float(uA << 16); a1 += __uint_as_float(uA & 0xffff0000u);
      b0 += __uint_as_float(uB << 16); b1 += __uint_as_float(uB & 0xffff0000u);
      c0 += __uint_as_float(uC << 16); c1 += __uint_as_float(uC & 0xffff0000u);
      d0 += __uint_as_float(uD << 16); d1 += __uint_as_float(uD & 0xffff0000u);
    }
    for (; e < cnt; ++e) {
      const int sA = __shfl(idx, e, 64);
      const unsigned uA = xw[(size_t)sA * 64 + lane];
      a0 += __uint_as_float(uA << 16); a1 += __uint_as_float(uA & 0xffff0000u);
    }
  }
  const float r0 = (a0 + b0) + (c0 + d0);
  const float r1 = (a1 + b1) + (c1 + d1);
  const int deg = s1 - s0;
  const float inv = (deg > 0) ? 1.0f / (float)deg : 0.0f;
  const unsigned lo = f2bf(r0 * inv), hi = f2bf(r1 * inv);
  ((unsigned*)meanb)[(size_t)wid * 64 + lane] = lo | (hi << 16);
}

// ---------------- weight prep: transposed bf16 concatenated weights ----------------
__global__ void build_w1cat_t(const float* __restrict__ Wl, const float* __restrict__ Wr,
                              unsigned short* __restrict__ BT) {
  int idx = blockIdx.x * blockDim.x + threadIdx.x;
  if (idx < 256 * 256) {
    int j = idx >> 8, k = idx & 255;
    float v = (k < 128) ? Wl[k * 256 + j] : Wr[(k - 128) * 256 + j];
    BT[idx] = f2bf(v);
  }
}
__global__ void build_w2cat_t(const float* __restrict__ Wl, const float* __restrict__ Wr,
                              unsigned short* __restrict__ BT) {
  int idx = blockIdx.x * blockDim.x + threadIdx.x;
  if (idx < 128 * 256) {
    int j = idx >> 8, k = idx & 255;
    float v = 0.f;
    if (j < OUT_C)           v = Wl[k * OUT_C + j];
    else if (j < 2 * OUT_C)  v = Wr[k * OUT_C + (j - OUT_C)];
    BT[idx] = f2bf(v);
  }
}

// ---------------- MFMA GEMM: C[M,ONC] = A[M,256] @ BT[ONC,256]^T (bf16 in, bf16 out) ----------------
template<int MODE>
__global__ __launch_bounds__(256) void gemm_mfma(const unsigned short* __restrict__ A0,
                                                 const unsigned short* __restrict__ A1,
                                                 const unsigned short* __restrict__ BT,
                                                 const float* __restrict__ bias,
                                                 unsigned short* __restrict__ Out,
                                                 int M) {
  constexpr int ONC = (MODE == 0) ? 256 : 128;
  __shared__ unsigned short Asl[128 * 64];
  __shared__ unsigned short Bsl[128 * 64];
  const int tid  = threadIdx.x;
  const int wid  = tid >> 6, lane = tid & 63;
  const int wm   = wid >> 1, wn = wid & 1;
  const int r0   = blockIdx.x * 128;
  const int c0   = blockIdx.y * 128;

  f32x4 acc[4][4];
  #pragma unroll
  for (int m = 0; m < 4; ++m)
    #pragma unroll
    for (int n = 0; n < 4; ++n)
      #pragma unroll
      for (int j = 0; j < 4; ++j) acc[m][n][j] = 0.f;

  const int srow = lane >> 3;
  const int cs   = (lane & 7) ^ srow;
  const int fr   = lane & 15;
  const int klo  = (lane >> 4) * 16;
  const int swz  = (fr & 7) << 4;

  #pragma unroll 1
  for (int kb = 0; kb < 4; ++kb) {
    const unsigned short* Ap;
    int acol, ak;
    if (MODE == 0) { Ap = (kb < 2) ? A0 : A1; acol = (kb & 1) * 64; ak = 128; }
    else           { Ap = A0;                 acol = kb * 64;       ak = 256; }
    #pragma unroll
    for (int i = 0; i < 4; ++i) {
      const int rl = wid * 32 + i * 8 + srow;
      int gr = r0 + rl; if (gr > M - 1) gr = M - 1;
      const unsigned short* gsa = Ap + (size_t)gr * ak + acol + cs * 8;
      __builtin_amdgcn_global_load_lds(
          (const __attribute__((address_space(1))) unsigned int*)gsa,
          (__attribute__((address_space(3))) unsigned int*)&Asl[(wid * 32 + i * 8) * 64],
          16, 0, 0);
      const unsigned short* gsb = BT + (size_t)(c0 + rl) * 256 + kb * 64 + cs * 8;
      __builtin_amdgcn_global_load_lds(
          (const __attribute__((address_space(1))) unsigned int*)gsb,
          (__attribute__((address_space(3))) unsigned int*)&Bsl[(wid * 32 + i * 8) * 64],
          16, 0, 0);
    }
    asm volatile("s_waitcnt vmcnt(0)");
    __syncthreads();
    #pragma unroll
    for (int ks = 0; ks < 2; ++ks) {
      bf16x8 af[4], bfv[4];
      #pragma unroll
      for (int m = 0; m < 4; ++m) {
        const int ro = (wm * 64 + m * 16 + fr) * 128 + ((ks * 64 + klo) ^ swz);
        af[m] = *(const bf16x8*)((const char*)Asl + ro);
      }
      #pragma unroll
      for (int n = 0; n < 4; ++n) {
        const int ro = (wn * 64 + n * 16 + fr) * 128 + ((ks * 64 + klo) ^ swz);
        bfv[n] = *(const bf16x8*)((const char*)Bsl + ro);
      }
      #pragma unroll
      for (int m = 0; m < 4; ++m)
        #pragma unroll
        for (int n = 0; n < 4; ++n)
          acc[m][n] = __builtin_amdgcn_mfma_f32_16x16x32_bf16(af[m], bfv[n], acc[m][n], 0, 0, 0);
    }
    __syncthreads();
  }

  const int orow0 = r0 + wm * 64 + (lane >> 4) * 4;
  const int ocol0 = c0 + wn * 64 + (lane & 15);
  #pragma unroll
  for (int m = 0; m < 4; ++m) {
    #pragma unroll
    for (int n = 0; n < 4; ++n) {
      const int col = ocol0 + n * 16;
      const float badd = (MODE == 0) ? bias[col] : 0.f;
      #pragma unroll
      for (int j = 0; j < 4; ++j) {
        const int row = orow0 + m * 16 + j;
        if (row < M) {
          float v = acc[m][n][j] + badd;
          if (MODE == 0) v = fmaxf(v, 0.f);
          Out[(size_t)row * ONC + col] = f2bf(v);
        }
      }
    }
  }
}

// ---------------- final: agg2 + bias + root + log_softmax ----------------
// Same gather-MLP structure as agg1: bulk index load + 4-edge unroll, 4 sums.
__global__ __launch_bounds__(256) void final_kernel(const unsigned short* __restrict__ Ob,
                                                    const int* __restrict__ off,
                                                    const int* __restrict__ csr,
                                                    const float* __restrict__ b2,
                                                    float* __restrict__ out, int N) {
  const int wid  = (blockIdx.x * blockDim.x + threadIdx.x) >> 6;
  const int lane = threadIdx.x & 63;
  if (wid >= N) return;
  const int s0 = off[wid], s1 = off[wid + 1];
  const bool act = lane < OUT_C;
  const int cl = act ? lane : 0;
  float t0 = 0.f, t1 = 0.f, t2 = 0.f, t3 = 0.f;
  for (int base = s0; base < s1; base += 64) {
    const int cnt = min(64, s1 - base);
    const int idx = (lane < cnt) ? csr[base + lane] : 0;   // coalesced bulk index load
    int e = 0;
    for (; e + 4 <= cnt; e += 4) {
      const int sA = __shfl(idx, e, 64),     sB = __shfl(idx, e + 1, 64);
      const int sC = __shfl(idx, e + 2, 64), sD = __shfl(idx, e + 3, 64);
      if (act) {
        t0 += bf2f(Ob[(size_t)sA * 128 + lane]);
        t1 += bf2f(Ob[(size_t)sB * 128 + lane]);
        t2 += bf2f(Ob[(size_t)sC * 128 + lane]);
        t3 += bf2f(Ob[(size_t)sD * 128 + lane]);
      }
    }
    for (; e < cnt; ++e) {
      const int sA = __shfl(idx, e, 64);
      if (act) t0 += bf2f(Ob[(size_t)sA * 128 + lane]);
    }
  }
  const float sum = (t0 + t1) + (t2 + t3);
  const int deg = s1 - s0;
  const float inv = (deg > 0) ? 1.0f / (float)deg : 0.0f;
  float v = sum * inv + b2[cl] + bf2f(Ob[(size_t)wid * 128 + OUT_C + cl]);
  if (!act) v = -INFINITY;
  float m = v;
  #pragma unroll
  for (int o = 32; o > 0; o >>= 1) m = fmaxf(m, __shfl_xor(m, o, 64));
  float ex = act ? expf(v - m) : 0.f;
  float s = ex;
  #pragma unroll
  for (int o = 32; o > 0; o >>= 1) s += __shfl_xor(s, o, 64);
  if (act) out[(size_t)wid * OUT_C + lane] = v - m - logf(s);
}

// ---------------- launch ----------------

extern "C" void kernel_launch(void* const* d_in, const int* in_sizes, int n_in,
                              void* d_out, int out_size, void* d_ws, size_t ws_size,
                              hipStream_t stream) {
  const float* x   = (const float*)d_in[0];
  const int*   ei  = (const int*)d_in[1];
  const float* W1l = (const float*)d_in[2];
  const float* b1  = (const float*)d_in[3];
  const float* W1r = (const float*)d_in[4];
  const float* W2l = (const float*)d_in[5];
  const float* b2  = (const float*)d_in[6];
  const float* W2r = (const float*)d_in[7];
  float* out = (float*)d_out;

  const int N = in_sizes[0] / IN_C;
  const int E = in_sizes[1] / 2;
  const int* src = ei;
  const int* dst = ei + E;

  char* base = (char*)d_ws;
  size_t o = 0;
  auto take = [&](size_t bytes) -> char* {
    char* p = base + o;
    o = (o + bytes + 255) & ~(size_t)255;
    return p;
  };
  int* cnt    = (int*)take((size_t)N * 4);
  int* cursor = (int*)take((size_t)N * 4);
  const size_t zero_bytes = o;
  int* off    = (int*)take((size_t)(N + 1) * 4);
  int* part   = (int*)take((size_t)1024 * 4);
  int* csr    = (int*)take((size_t)E * 4);
  unsigned short* xb    = (unsigned short*)take((size_t)N * IN_C * 2);
  unsigned short* meanb = (unsigned short*)take((size_t)N * IN_C * 2);
  unsigned short* h     = (unsigned short*)take((size_t)N * HID_C * 2);
  unsigned short* W1T   = (unsigned short*)take((size_t)256 * 256 * 2);
  unsigned short* W2T   = (unsigned short*)take((size_t)128 * 256 * 2);
  unsigned short* Ocat  = meanb;   // alias: meanb dead after gemm1
  (void)ws_size; (void)n_in; (void)out_size;

  hipMemsetAsync(base, 0, zero_bytes, stream);

  const int tb = 256;
  const int nb = (N + 1023) / 1024;
  count_edges<<<(E + tb - 1) / tb, tb, 0, stream>>>(dst, cnt, E);
  scan_partials<<<nb, 256, 0, stream>>>(cnt, part, N);
  scan_roots<<<1, 1024, 0, stream>>>(part, off, nb, N);
  scan_write<<<nb, 256, 0, stream>>>(cnt, part, off, N);
  fill_csr<<<(E + tb - 1) / tb, tb, 0, stream>>>(src, dst, off, cursor, csr, E);

  const int n4 = N * IN_C / 4;
  f32_to_bf16<<<(n4 + tb - 1) / tb, tb, 0, stream>>>(x, xb, n4);
  build_w1cat_t<<<256, 256, 0, stream>>>(W1l, W1r, W1T);
  build_w2cat_t<<<128, 256, 0, stream>>>(W2l, W2r, W2T);

  agg1<<<(N + 3) / 4, 256, 0, stream>>>(xb, off, csr, meanb, N);

  const int mb = (N + 127) / 128;
  gemm_mfma<0><<<dim3(mb, 2), 256, 0, stream>>>(meanb, xb, W1T, b1, h, N);
  gemm_mfma<1><<<dim3(mb, 1), 256, 0, stream>>>(h, nullptr, W2T, nullptr, Ocat, N);

  final_kernel<<<(N + 3) / 4, 256, 0, stream>>>(Ocat, off, csr, b2, out, N);
}